// Round 1
// baseline (493.059 us; speedup 1.0000x reference)
//
#include <hip/hip_runtime.h>
#include <math.h>

// Problem constants (from reference)
#define B_ 4096
#define T_ 1024
#define I_ 6
#define H_ 2
#define L_ 5
#define G_ 8   // 4*H packed gates: rows 0-1=i, 2-3=f, 4-5=g, 6-7=o

// Only batch element B-1 affects the output (softmax(seq[-1,-1])):
// LSTM is batch-independent, so we process exactly one sequence.
//
// Lane layout (single wave of 64): lane = 8*l + g, l in [0,5), g in [0,8).
// Diagonal pipeline: at step s, layer l processes t = s - l.
// Layer l reads h_{l-1}[t] via shuffle from lanes 8(l-1)+{0,1}, which
// updated at step s-1 with exactly timestep t. Lanes g in {0,1} of each
// group carry (h_j, c_j) for hidden unit j.

__global__ __launch_bounds__(256) void lstm_kernel(
    const float* __restrict__ x,
    const float* __restrict__ Wih0,
    const float* __restrict__ Wih,
    const float* __restrict__ Whh,
    const float* __restrict__ bih,
    const float* __restrict__ bhh,
    float* __restrict__ out)
{
    __shared__ float pre0[T_ * G_];   // 32 KB: layer-0 preactivations, all t
    const int tid = threadIdx.x;
    const float* xrow = x + (size_t)(B_ - 1) * T_ * I_;   // x[B-1, :, :]

    // ---- parallel phase: pre0[t][g] = Wih0[g,:]·x[B-1,t,:] + bih0[g] + bhh0[g]
    float w0[G_][I_];
    float b0[G_];
    #pragma unroll
    for (int g = 0; g < G_; ++g) {
        b0[g] = bih[g] + bhh[g];
        #pragma unroll
        for (int k = 0; k < I_; ++k)
            w0[g][k] = Wih0[g * I_ + k];
    }
    for (int t = tid; t < T_; t += 256) {
        float xv[I_];
        #pragma unroll
        for (int k = 0; k < I_; ++k) xv[k] = xrow[t * I_ + k];
        #pragma unroll
        for (int g = 0; g < G_; ++g) {
            float acc = b0[g];
            #pragma unroll
            for (int k = 0; k < I_; ++k) acc = fmaf(xv[k], w0[g][k], acc);
            pre0[t * G_ + g] = acc;
        }
    }
    __syncthreads();
    if (tid >= 64) return;   // serial phase: one wave only

    // ---- serial phase: layer-pipelined recurrence
    const int lane = tid;
    const int l = lane >> 3;          // layer (0..4 valid; 5..7 idle)
    const int g = lane & 7;           // gate row within layer
    const bool lv = (l < L_);

    float whh0 = 0.f, whh1 = 0.f, wi0 = 0.f, wi1 = 0.f, bsum = 0.f;
    if (lv) {
        whh0 = Whh[l * (G_ * H_) + g * H_ + 0];
        whh1 = Whh[l * (G_ * H_) + g * H_ + 1];
        if (l > 0) {
            wi0  = Wih[(l - 1) * (G_ * H_) + g * H_ + 0];
            wi1  = Wih[(l - 1) * (G_ * H_) + g * H_ + 1];
            bsum = bih[l * G_ + g] + bhh[l * G_ + g];
        }
    }
    const int prevBase = (l > 0 ? (l - 1) : 0) * 8;  // clamp; unused when l==0
    const int ownBase  = l * 8;
    const int j = g & 1;               // hidden-unit index for gate combine

    float h = 0.f, c = 0.f;            // valid in lanes g in {0,1}
    for (int s = 0; s < T_ + L_ - 1; ++s) {
        const int t = s - l;
        // read OLD h values (previous step) before any update
        const float hin0 = __shfl(h, prevBase + 0, 64);
        const float hin1 = __shfl(h, prevBase + 1, 64);
        const float h0o  = __shfl(h, ownBase + 0, 64);
        const float h1o  = __shfl(h, ownBase + 1, 64);

        float p;
        if (l == 0) {
            p = (t < T_) ? pre0[((t & (T_ - 1)) << 3) + g] : 0.f;
        } else {
            p = fmaf(wi1, hin1, fmaf(wi0, hin0, bsum));
        }
        const float a = fmaf(whh1, h1o, fmaf(whh0, h0o, p));
        // rows 4,5 are the 'g' gate -> tanh; others sigmoid
        const float actv = (g == 4 || g == 5) ? tanhf(a)
                                              : (1.f / (1.f + expf(-a)));
        const float iv = __shfl(actv, ownBase + 0 + j, 64);
        const float fv = __shfl(actv, ownBase + 2 + j, 64);
        const float gv = __shfl(actv, ownBase + 4 + j, 64);
        const float ov = __shfl(actv, ownBase + 6 + j, 64);

        if (lv && g < 2 && t >= 0 && t < T_) {
            c = fmaf(fv, c, iv * gv);
            h = ov * tanhf(c);
        }
    }

    // final hidden of layer 4 lives in lanes 32 (unit 0) and 33 (unit 1)
    const float hf0 = __shfl(h, 4 * 8 + 0, 64);
    const float hf1 = __shfl(h, 4 * 8 + 1, 64);
    if (lane == 0) {
        const float m  = fmaxf(hf0, hf1);
        const float e0 = expf(hf0 - m);
        const float e1 = expf(hf1 - m);
        const float inv = 1.f / (e0 + e1);
        out[0] = e0 * inv;
        out[1] = e1 * inv;
    }
}

extern "C" void kernel_launch(void* const* d_in, const int* in_sizes, int n_in,
                              void* d_out, int out_size, void* d_ws, size_t ws_size,
                              hipStream_t stream) {
    const float* x    = (const float*)d_in[0];
    // d_in[1] = hidden (unused by the reference forward)
    const float* Wih0 = (const float*)d_in[2];
    const float* Wih  = (const float*)d_in[3];
    const float* Whh  = (const float*)d_in[4];
    const float* bih  = (const float*)d_in[5];
    const float* bhh  = (const float*)d_in[6];
    float* out = (float*)d_out;

    lstm_kernel<<<1, 256, 0, stream>>>(x, Wih0, Wih, Whh, bih, bhh, out);
}

// Round 2
// 262.267 us; speedup vs baseline: 1.8800x; 1.8800x over previous
//
#include <hip/hip_runtime.h>
#include <math.h>

// Problem constants (from reference)
#define B_ 4096
#define T_ 1024
#define I_ 6
#define H_ 2
#define L_ 5
#define G_ 8            // 4*H packed gates, PyTorch order: rows 0-1=i, 2-3=f, 4-5=g, 6-7=o
#define S_ (T_ + L_ - 1) // 1028 pipelined steps

// Only batch element B-1 affects the output (softmax(seq[-1,-1])); LSTM is
// batch-independent, so we process exactly one sequence.
//
// Serial phase layout: lane = 2*l + j  (layer l in [0,5), hidden unit j in {0,1}).
// All 10 active lanes live in DPP row 0 (lanes 0-15), so ALL cross-lane traffic
// uses DPP (VALU-latency) instead of ds_bpermute (LDS-latency):
//   - within-layer h swap: quad_perm [1,0,3,2]  (ctrl 0xB1)
//   - cross-layer h pass:  row_shr:2            (ctrl 0x112)
// Each lane computes its unit's 4 gates + cell update entirely in-lane with
// branch-free fast activations (v_exp_f32 + v_rcp_f32), so there is no
// divergence and no second shuffle round.

template <int CTRL>
__device__ __forceinline__ float dppf(float v) {
    int i = __float_as_int(v);
    int r = __builtin_amdgcn_update_dpp(i, i, CTRL, 0xF, 0xF, false);
    return __int_as_float(r);
}

__device__ __forceinline__ float fast_sigmoid(float x) {
    // 1 / (1 + 2^(-x*log2(e)))
    float e = __builtin_amdgcn_exp2f(-1.442695041f * x);
    return __builtin_amdgcn_rcpf(1.0f + e);
}
__device__ __forceinline__ float fast_tanh(float x) {
    // 2*sigmoid(2x) - 1
    float e = __builtin_amdgcn_exp2f(-2.885390082f * x);
    return fmaf(2.0f, __builtin_amdgcn_rcpf(1.0f + e), -1.0f);
}

__global__ __launch_bounds__(256) void lstm_kernel(
    const float* __restrict__ x,
    const float* __restrict__ Wih0,
    const float* __restrict__ Wih,
    const float* __restrict__ Whh,
    const float* __restrict__ bih,
    const float* __restrict__ bhh,
    float* __restrict__ out)
{
    // Layer-0 preactivations, unit-major per t: pre0[t*8 + j*4 + q], row = 2q+j.
    // +8 t-slots of zero padding so the unroll-2 prefetch never reads OOB.
    __shared__ float pre0[(T_ + 8) * G_];
    __shared__ float zbias[32];      // bias sums for lanes 2..9 (layers 1..4), 4 floats each
    const int tid = threadIdx.x;
    const float* xrow = x + (size_t)(B_ - 1) * T_ * I_;   // x[B-1, :, :]

    // ---- parallel phase: layer-0 input projections for all t
    float w0[G_][I_];
    float b0[G_];
    #pragma unroll
    for (int j = 0; j < 2; ++j)
        #pragma unroll
        for (int q = 0; q < 4; ++q) {
            const int m = j * 4 + q, row = 2 * q + j;
            b0[m] = bih[row] + bhh[row];
            #pragma unroll
            for (int k = 0; k < I_; ++k) w0[m][k] = Wih0[row * I_ + k];
        }
    for (int t = tid; t < T_; t += 256) {
        float xv[I_];
        #pragma unroll
        for (int k = 0; k < I_; ++k) xv[k] = xrow[t * I_ + k];
        #pragma unroll
        for (int m = 0; m < G_; ++m) {
            float acc = b0[m];
            #pragma unroll
            for (int k = 0; k < I_; ++k) acc = fmaf(xv[k], w0[m][k], acc);
            pre0[t * G_ + m] = acc;
        }
    }
    if (tid < 64) pre0[T_ * G_ + tid] = 0.f;   // zero the pad slots
    if (tid < 32) {
        // zbias[(lane-2)*4 + q] for lane in [2,10): layer l=lane>>1, unit j=lane&1
        const int L = 2 + (tid >> 2), q = tid & 3;
        const int l = L >> 1, j = L & 1, row = 2 * q + j;
        zbias[tid] = bih[l * G_ + row] + bhh[l * G_ + row];
    }
    __syncthreads();
    if (tid >= 64) return;   // serial phase: one wave

    // ---- per-lane constants
    const int lane = tid;
    const int lraw = lane >> 1;
    const int l = (lraw < L_) ? lraw : (L_ - 1);   // clamp for don't-care lanes >= 10
    const int j = lane & 1;

    // Weight order compensates for (own, other) register layout per parity.
    float wOwn[4], wOth[4], wiOwn[4], wiOth[4];
    #pragma unroll
    for (int q = 0; q < 4; ++q) {
        const int row = 2 * q + j;
        wOwn[q] = Whh[l * (G_ * H_) + row * H_ + j];
        wOth[q] = Whh[l * (G_ * H_) + row * H_ + (1 - j)];
        if (l > 0) {
            wiOwn[q] = Wih[(l - 1) * (G_ * H_) + row * H_ + j];
            wiOth[q] = Wih[(l - 1) * (G_ * H_) + row * H_ + (1 - j)];
        } else {
            wiOwn[q] = 0.f; wiOth[q] = 0.f;   // layer 0: input term comes from pre0
        }
    }

    // LDS base pointer: lanes 0,1 walk pre0 (stride 32B); others read their
    // constant bias quad every iteration (stride 0). Uniform code, no branches.
    const float4* p;
    int stride4;
    if (lane < 2) { p = (const float4*)&pre0[lane * 4]; stride4 = 2; }
    else          { p = (const float4*)&zbias[((lane < 10 ? lane : 9) - 2) * 4]; stride4 = 0; }

    float h = 0.f, c = 0.f, hoth = 0.f;
    int t = -l;                          // lane's local timestep (valid when 0<=t<T)
    float4 bA = p[0]; p += stride4;      // base for step s
    float4 bB = p[0]; p += stride4;      // base for step s+1

#define STEP(BASE)                                                          \
    {                                                                       \
        float4 cur = (BASE);                                                \
        (BASE) = p[0]; p += stride4;  /* prefetch for s+2 */                \
        const float hin0 = dppf<0x112>(h);     /* prev layer, unit j   */   \
        const float hin1 = dppf<0x112>(hoth);  /* prev layer, unit 1-j */   \
        float a0 = fmaf(wiOth[0], hin1, fmaf(wiOwn[0], hin0, cur.x));       \
        float a1 = fmaf(wiOth[1], hin1, fmaf(wiOwn[1], hin0, cur.y));       \
        float a2 = fmaf(wiOth[2], hin1, fmaf(wiOwn[2], hin0, cur.z));       \
        float a3 = fmaf(wiOth[3], hin1, fmaf(wiOwn[3], hin0, cur.w));       \
        a0 = fmaf(wOth[0], hoth, fmaf(wOwn[0], h, a0));                     \
        a1 = fmaf(wOth[1], hoth, fmaf(wOwn[1], h, a1));                     \
        a2 = fmaf(wOth[2], hoth, fmaf(wOwn[2], h, a2));                     \
        a3 = fmaf(wOth[3], hoth, fmaf(wOwn[3], h, a3));                     \
        const float iv = fast_sigmoid(a0);                                  \
        const float fv = fast_sigmoid(a1);                                  \
        const float gv = fast_tanh(a2);                                     \
        const float ov = fast_sigmoid(a3);                                  \
        const float cn = fmaf(fv, c, iv * gv);                              \
        const float hn = ov * fast_tanh(cn);                                \
        const bool valid = ((unsigned)t < (unsigned)T_);                    \
        c = valid ? cn : c;                                                 \
        h = valid ? hn : h;                                                 \
        hoth = dppf<0xB1>(h);          /* within-layer swap */              \
        ++t;                                                                \
    }

    for (int s = 0; s < S_; s += 2) {
        STEP(bA)
        STEP(bB)
    }
#undef STEP

    // layer 4 = lanes 8 (unit 0) and 9 (unit 1)
    const float hf0 = __shfl(h, 8, 64);
    const float hf1 = __shfl(h, 9, 64);
    if (lane == 0) {
        const float m  = fmaxf(hf0, hf1);
        const float e0 = __builtin_amdgcn_exp2f(1.442695041f * (hf0 - m));
        const float e1 = __builtin_amdgcn_exp2f(1.442695041f * (hf1 - m));
        const float inv = 1.f / (e0 + e1);
        out[0] = e0 * inv;
        out[1] = e1 * inv;
    }
}

extern "C" void kernel_launch(void* const* d_in, const int* in_sizes, int n_in,
                              void* d_out, int out_size, void* d_ws, size_t ws_size,
                              hipStream_t stream) {
    const float* x    = (const float*)d_in[0];
    // d_in[1] = hidden (unused by the reference forward)
    const float* Wih0 = (const float*)d_in[2];
    const float* Wih  = (const float*)d_in[3];
    const float* Whh  = (const float*)d_in[4];
    const float* bih  = (const float*)d_in[5];
    const float* bhh  = (const float*)d_in[6];
    float* out = (float*)d_out;

    lstm_kernel<<<1, 256, 0, stream>>>(x, Wih0, Wih, Whh, bih, bhh, out);
}

// Round 3
// 217.262 us; speedup vs baseline: 2.2694x; 1.2071x over previous
//
#include <hip/hip_runtime.h>
#include <math.h>

// Problem constants (from reference)
#define B_ 4096
#define T_ 1024
#define I_ 6
#define H_ 2
#define L_ 5
#define G_ 8            // 4*H packed gates, PyTorch order: rows 0-1=i, 2-3=f, 4-5=g, 6-7=o
#define S_ (T_ + L_ - 1) // 1028 pipelined steps

// Only batch element B-1 affects the output (softmax(seq[-1,-1])); LSTM is
// batch-independent -> process exactly one sequence.
//
// Serial phase: lane = 2*l + j (layer l, hidden unit j). All cross-lane
// traffic is DPP: hin0 = row_shr:2 (prev layer, own unit), hin1 =
// quad_perm-swap of hin0 (prev layer, other unit), hoth = quad_perm-swap
// of h. ALL weights/biases (and the precomputed layer-0 stream) are
// pre-scaled by -log2(e) (sigmoid gates i,f,o) or -2*log2(e) (g gate),
// so activations are exp2 -> add -> rcp with no multiply:
//   sigma(a) = rcp(1 + exp2(a'))        [a' = -log2e * a]
//   tanh(a)  = 2*rcp(1 + exp2(a'')) - 1 [a'' = -2log2e * a]
// Warmup (t<0) is handled by 4 peeled masked steps; drain (t>=T) needs no
// mask: stale h values only flow toward higher layers at t>=T, which never
// reach the final (layer 4, t=T-1) output, and pre0's pad rows are zero.

typedef float v2f __attribute__((ext_vector_type(2)));

#define K1 1.4426950408889634f   /* log2(e)   */
#define K2 2.8853900817779268f   /* 2*log2(e) */

template <int CTRL>
__device__ __forceinline__ float dppf(float v) {
    int i = __float_as_int(v);
    int r = __builtin_amdgcn_update_dpp(i, i, CTRL, 0xF, 0xF, false);
    return __int_as_float(r);
}
#define DPP_SHR2 0x112   /* row_shr:2            */
#define DPP_SWAP 0xB1    /* quad_perm [1,0,3,2]  */

__global__ __launch_bounds__(256) void lstm_kernel(
    const float* __restrict__ x,
    const float* __restrict__ Wih0,
    const float* __restrict__ Wih,
    const float* __restrict__ Whh,
    const float* __restrict__ bih,
    const float* __restrict__ bhh,
    float* __restrict__ out)
{
    // pre0[t*8 + j*4 + q]: pre-scaled layer-0 preactivation, row = 2q+j.
    // 8 extra t-slots of zeros so distance-4 prefetch never reads live data OOB.
    __shared__ float pre0[(T_ + 8) * G_];
    // Per-serial-lane (2..9) bias block: 4 identical float4 copies at 32B
    // spacing so ds_read offset immediates 0/32/64/96 all hit the bias.
    // Block stride 36 floats (144B) to spread LDS banks.
    __shared__ float zrep[8 * 36 + 12];

    const int tid = threadIdx.x;
    const float* xrow = x + (size_t)(B_ - 1) * T_ * I_;   // x[B-1, :, :]
    const float sc[4] = { -K1, -K1, -K2, -K1 };           // i, f, g, o

    // ---- parallel phase: pre-scaled layer-0 input projections for all t
    float w0s[G_][I_];
    float b0s[G_];
    #pragma unroll
    for (int j = 0; j < 2; ++j)
        #pragma unroll
        for (int q = 0; q < 4; ++q) {
            const int m = j * 4 + q, row = 2 * q + j;
            const float s = sc[q];
            b0s[m] = s * (bih[row] + bhh[row]);
            #pragma unroll
            for (int k = 0; k < I_; ++k) w0s[m][k] = s * Wih0[row * I_ + k];
        }
    for (int t = tid; t < T_; t += 256) {
        float xv[I_];
        #pragma unroll
        for (int k = 0; k < I_; ++k) xv[k] = xrow[t * I_ + k];
        #pragma unroll
        for (int m = 0; m < G_; ++m) {
            float acc = b0s[m];
            #pragma unroll
            for (int k = 0; k < I_; ++k) acc = fmaf(xv[k], w0s[m][k], acc);
            pre0[t * G_ + m] = acc;
        }
    }
    if (tid < 64) pre0[T_ * G_ + tid] = 0.f;   // zero pad slots
    if (tid < 128) {
        // zrep for serial lane zl+2: layer l=(zl+2)>>1, unit j=(zl+2)&1
        const int zl = tid >> 4, k = (tid >> 2) & 3, q = tid & 3;
        const int l = (zl + 2) >> 1, j = (zl + 2) & 1, row = 2 * q + j;
        zrep[zl * 36 + k * 8 + q] = sc[q] * (bih[l * G_ + row] + bhh[l * G_ + row]);
    }
    __syncthreads();
    if (tid >= 64) return;   // serial phase: one wave

    // ---- per-lane constants (pre-scaled weights)
    const int lane = tid;
    const int lraw = lane >> 1;
    const int l = (lraw < L_) ? lraw : (L_ - 1);   // clamp for lanes >= 10
    const int j = lane & 1;

    float wOwn[4], wOth[4], wiOwn[4], wiOth[4];
    #pragma unroll
    for (int q = 0; q < 4; ++q) {
        const int row = 2 * q + j;
        const float s = sc[q];
        wOwn[q] = s * Whh[l * (G_ * H_) + row * H_ + j];
        wOth[q] = s * Whh[l * (G_ * H_) + row * H_ + (1 - j)];
        if (l > 0) {
            wiOwn[q] = s * Wih[(l - 1) * (G_ * H_) + row * H_ + j];
            wiOth[q] = s * Wih[(l - 1) * (G_ * H_) + row * H_ + (1 - j)];
        } else {
            wiOwn[q] = 0.f; wiOth[q] = 0.f;   // layer 0: input term is in pre0
        }
    }
    const v2f wOwn01  = { wOwn[0],  wOwn[1]  }, wOwn23  = { wOwn[2],  wOwn[3]  };
    const v2f wOth01  = { wOth[0],  wOth[1]  }, wOth23  = { wOth[2],  wOth[3]  };
    const v2f wiOwn01 = { wiOwn[0], wiOwn[1] }, wiOwn23 = { wiOwn[2], wiOwn[3] };
    const v2f wiOth01 = { wiOth[0], wiOth[1] }, wiOth23 = { wiOth[2], wiOth[3] };

    // Per-lane LDS stream: lanes 0,1 walk pre0 (128B per 4-step block);
    // lanes 2-9 sit on their replicated bias block (stride 0).
    const char* pb;
    int stB;
    if (lane < 2) { pb = (const char*)&pre0[lane * 4]; stB = 128; }
    else {
        const int zl = (lane < 10 ? lane : 9) - 2;
        pb = (const char*)&zrep[zl * 36]; stB = 0;
    }

#define LOADBLK(A,B,C,D)                                                    \
    { A = *(const float4*)(pb);      B = *(const float4*)(pb + 32);         \
      C = *(const float4*)(pb + 64); D = *(const float4*)(pb + 96);         \
      pb += stB; }

    float h = 0.f, c = 0.f, hoth = 0.f;

#define STEP_CORE(QX)                                                       \
        const float hin0 = dppf<DPP_SHR2>(h);                               \
        const v2f hv    = { h, h };                                         \
        const v2f hothv = { hoth, hoth };                                   \
        v2f a01 = { (QX).x, (QX).y };                                       \
        v2f a23 = { (QX).z, (QX).w };                                       \
        a01 = __builtin_elementwise_fma(wOwn01, hv, a01);                   \
        a23 = __builtin_elementwise_fma(wOwn23, hv, a23);                   \
        a01 = __builtin_elementwise_fma(wOth01, hothv, a01);                \
        a23 = __builtin_elementwise_fma(wOth23, hothv, a23);                \
        const v2f hin0v = { hin0, hin0 };                                   \
        a01 = __builtin_elementwise_fma(wiOwn01, hin0v, a01);               \
        a23 = __builtin_elementwise_fma(wiOwn23, hin0v, a23);               \
        const float hin1 = dppf<DPP_SWAP>(hin0);                            \
        const v2f hin1v = { hin1, hin1 };                                   \
        a01 = __builtin_elementwise_fma(wiOth01, hin1v, a01);               \
        a23 = __builtin_elementwise_fma(wiOth23, hin1v, a23);               \
        const float e0 = __builtin_amdgcn_exp2f(a01.x);                     \
        const float e1 = __builtin_amdgcn_exp2f(a01.y);                     \
        const float e2 = __builtin_amdgcn_exp2f(a23.x);                     \
        const float e3 = __builtin_amdgcn_exp2f(a23.y);                     \
        const float iv = __builtin_amdgcn_rcpf(1.0f + e0);                  \
        const float fv = __builtin_amdgcn_rcpf(1.0f + e1);                  \
        const float r2 = __builtin_amdgcn_rcpf(1.0f + e2);                  \
        const float ov = __builtin_amdgcn_rcpf(1.0f + e3);                  \
        const float gv = fmaf(2.0f, r2, -1.0f);                             \
        const float cn = fmaf(fv, c, iv * gv);                              \
        const float eh = __builtin_amdgcn_exp2f(-K2 * cn);                  \
        const float rh = __builtin_amdgcn_rcpf(1.0f + eh);                  \
        const float th = fmaf(2.0f, rh, -1.0f);

#define STEP(QX)                                                            \
    {                                                                       \
        STEP_CORE(QX)                                                       \
        c = cn;                                                             \
        h = ov * th;                                                        \
        hoth = dppf<DPP_SWAP>(h);                                           \
    }

#define STEP_M(QX, S)                                                       \
    {                                                                       \
        STEP_CORE(QX)                                                       \
        const bool valid = ((S) >= lraw);                                   \
        c = valid ? cn : 0.0f;                                              \
        h = valid ? (ov * th) : 0.0f;                                       \
        hoth = dppf<DPP_SWAP>(h);                                           \
    }

    float4 qa0, qa1, qa2, qa3, qb0, qb1, qb2, qb3;
    LOADBLK(qa0, qa1, qa2, qa3)        // block 0: steps 0..3
    LOADBLK(qb0, qb1, qb2, qb3)        // block 1: steps 4..7

    // peeled masked warmup (t<0 only possible for s<4)
    STEP_M(qa0, 0) STEP_M(qa1, 1) STEP_M(qa2, 2) STEP_M(qa3, 3)

    // steady: steps 4..1027, 128 iterations x 8 steps, double-buffered
    for (int it = 0; it < 128; ++it) {
        LOADBLK(qa0, qa1, qa2, qa3)    // block 2+2it (for steps +4)
        STEP(qb0) STEP(qb1) STEP(qb2) STEP(qb3)
        LOADBLK(qb0, qb1, qb2, qb3)    // block 3+2it
        STEP(qa0) STEP(qa1) STEP(qa2) STEP(qa3)
    }
#undef STEP
#undef STEP_M
#undef STEP_CORE
#undef LOADBLK

    // layer 4 = lanes 8 (unit 0) and 9 (unit 1)
    const float hf0 = __shfl(h, 8, 64);
    const float hf1 = __shfl(h, 9, 64);
    if (lane == 0) {
        const float m  = fmaxf(hf0, hf1);
        const float e0 = __builtin_amdgcn_exp2f(K1 * (hf0 - m));
        const float e1 = __builtin_amdgcn_exp2f(K1 * (hf1 - m));
        const float inv = 1.f / (e0 + e1);
        out[0] = e0 * inv;
        out[1] = e1 * inv;
    }
}

extern "C" void kernel_launch(void* const* d_in, const int* in_sizes, int n_in,
                              void* d_out, int out_size, void* d_ws, size_t ws_size,
                              hipStream_t stream) {
    const float* x    = (const float*)d_in[0];
    // d_in[1] = hidden (unused by the reference forward)
    const float* Wih0 = (const float*)d_in[2];
    const float* Wih  = (const float*)d_in[3];
    const float* Whh  = (const float*)d_in[4];
    const float* bih  = (const float*)d_in[5];
    const float* bhh  = (const float*)d_in[6];
    float* out = (float*)d_out;

    lstm_kernel<<<1, 256, 0, stream>>>(x, Wih0, Wih, Whh, bih, bhh, out);
}